// Round 1
// baseline (294.654 us; speedup 1.0000x reference)
//
#include <hip/hip_runtime.h>
#include <stdint.h>

#define N_NODES 16384
#define N_EDGES 4096
#define FDIM    128
#define EPSF    1e-6f

typedef __attribute__((ext_vector_type(8))) short short8;
typedef __attribute__((ext_vector_type(4))) float f32x4;

__device__ __forceinline__ unsigned short f2bf(float f) {
    uint32_t u = __float_as_uint(f);
    return (unsigned short)((u + 0x7FFFu + ((u >> 16) & 1u)) >> 16);  // RNE
}

// K1: bitpack H rows -> bitsNE [N][E/64], plus d_v_inv[n] via popcount (exact)
__global__ __launch_bounds__(256) void k_bitpack(const float* __restrict__ H,
        unsigned long long* __restrict__ bitsNE, float* __restrict__ dvinv) {
    int w = threadIdx.x >> 6, lane = threadIdx.x & 63;
    int n = blockIdx.x * 4 + w;
    const float* hr = H + (size_t)n * N_EDGES;
    unsigned long long* out = bitsNE + (size_t)n * (N_EDGES / 64);
    int cnt = 0;
    for (int c = 0; c < N_EDGES / 64; ++c) {
        float v = hr[c * 64 + lane];
        unsigned long long m = __ballot(v > 0.5f);
        cnt += __popcll(m);
        if (lane == 0) out[c] = m;
    }
    if (lane == 0) dvinv[n] = 1.0f / ((float)cnt + EPSF);
}

// K2: 64x64 bit-tile transpose: bitsNE [N][E/64] -> bitsEN [E][N/64]
__global__ __launch_bounds__(256) void k_transpose(const unsigned long long* __restrict__ bitsNE,
        unsigned long long* __restrict__ bitsEN) {
    int w = threadIdx.x >> 6, lane = threadIdx.x & 63;
    int wid = blockIdx.x * 4 + w;        // 16384 tiles
    int et = wid & 63, nt = wid >> 6;
    unsigned long long q = bitsNE[(size_t)(nt * 64 + lane) * (N_EDGES / 64) + et];
    unsigned long long outv = 0;
    for (int j = 0; j < 64; ++j) {
        unsigned long long r = __ballot((int)((q >> j) & 1ULL));
        if (lane == j) outv = r;
    }
    bitsEN[(size_t)(et * 64 + lane) * (N_NODES / 64) + nt] = outv;
}

// K3: edge degrees via popcount over bitsEN rows -> d_e_inv[e]
__global__ __launch_bounds__(256) void k_edeg(const unsigned long long* __restrict__ bitsEN,
        float* __restrict__ deinv) {
    int w = threadIdx.x >> 6, lane = threadIdx.x & 63;
    int e = blockIdx.x * 4 + w;
    const unsigned long long* r = bitsEN + (size_t)e * (N_NODES / 64);
    int s = __popcll(r[lane]) + __popcll(r[lane + 64]) + __popcll(r[lane + 128]) + __popcll(r[lane + 192]);
    for (int o = 32; o; o >>= 1) s += __shfl_xor(s, o);
    if (lane == 0) deinv[e] = 1.0f / ((float)s + EPSF);
}

// K4: xw = x @ W via bf16 MFMA; output stored TRANSPOSED bf16: xwT [128][N]
__global__ __launch_bounds__(256) void k_xw(const float* __restrict__ x, const float* __restrict__ W,
        unsigned short* __restrict__ xwT) {
    __shared__ __attribute__((aligned(16))) unsigned short ldsWT[128 * 136];
    __shared__ __attribute__((aligned(16))) unsigned short ldsT[128 * 72];
    int t = threadIdx.x, lane = t & 63, w = t >> 6;
    int r16 = lane & 15, klane = lane >> 4;
    // stage W^T (bf16) into LDS
    for (int i = 0; i < 64; ++i) {
        int idx = i * 256 + t;
        int k = idx >> 7, f = idx & 127;
        ldsWT[f * 136 + k] = f2bf(W[idx]);
    }
    __syncthreads();
    int nbase = blockIdx.x * 64;
    int row = nbase + w * 16 + r16;
    const float* xr = x + (size_t)row * FDIM;
    f32x4 acc[8] = {};
    for (int kb = 0; kb < 128; kb += 32) {
        union { short8 v; unsigned short u[8]; } a;
        #pragma unroll
        for (int j = 0; j < 8; ++j) a.u[j] = f2bf(xr[kb + klane * 8 + j]);
        #pragma unroll
        for (int fb = 0; fb < 8; ++fb) {
            short8 b = *(const short8*)&ldsWT[(fb * 16 + r16) * 136 + kb + klane * 8];
            acc[fb] = __builtin_amdgcn_mfma_f32_16x16x32_bf16(a.v, b, acc[fb], 0, 0, 0);
        }
    }
    // transpose epilogue via LDS, then coalesced bf16 writes
    #pragma unroll
    for (int fb = 0; fb < 8; ++fb)
        #pragma unroll
        for (int r = 0; r < 4; ++r)
            ldsT[(fb * 16 + r16) * 72 + w * 16 + klane * 4 + r] = f2bf(acc[fb][r]);
    __syncthreads();
    int f = t >> 1, part = t & 1;
    #pragma unroll
    for (int j = 0; j < 4; ++j)
        *(uint4*)&xwT[(size_t)f * N_NODES + nbase + part * 32 + j * 8] =
            *(const uint4*)&ldsT[f * 72 + part * 32 + j * 8];
}

// K5/K6: C[M,128] = bits(A:[M x K]) * B, with B given transposed bf16 BT=[128][K].
// FINAL: fuse rowScale and write fp32 out; else write split-K fp32 partials.
template<bool FINAL>
__global__ __launch_bounds__(256) void k_gemm_bits(
        const unsigned long long* __restrict__ bits, int krows /* K/64 */,
        const unsigned short* __restrict__ BT, int K,
        float* __restrict__ Cout, const float* __restrict__ rowScale,
        int M, int pairs) {
    __shared__ __attribute__((aligned(16))) unsigned short ldsB[128 * 72];
    int t = threadIdx.x, lane = t & 63, w = t >> 6;
    int r16 = lane & 15, klane = lane >> 4;
    int fh = (w & 1) * 64;
    int mbase = blockIdx.x * 32 + (w >> 1) * 16;
    int kq0 = blockIdx.z * pairs;
    const unsigned long long* brow = bits + (size_t)(mbase + r16) * krows + kq0;
    int srow = t >> 1, shalf = t & 1;
    const unsigned short* sBT = BT + (size_t)srow * K + shalf * 32;
    unsigned short* sL = ldsB + srow * 72 + shalf * 32;
    f32x4 acc[4] = {};
    for (int p = 0; p < pairs; ++p) {
        int kb = (kq0 + p) * 64;
        const unsigned short* src = sBT + kb;
        uint4 v0 = *(const uint4*)(src);
        uint4 v1 = *(const uint4*)(src + 8);
        uint4 v2 = *(const uint4*)(src + 16);
        uint4 v3 = *(const uint4*)(src + 24);
        unsigned long long q = brow[p];
        *(uint4*)(sL) = v0; *(uint4*)(sL + 8) = v1;
        *(uint4*)(sL + 16) = v2; *(uint4*)(sL + 24) = v3;
        __syncthreads();
        #pragma unroll
        for (int s = 0; s < 2; ++s) {
            uint32_t b8 = (uint32_t)(q >> (s * 32 + klane * 8)) & 0xFFu;
            union { short8 v; uint32_t u[4]; } a;
            a.u[0] = ((b8 & 1u)  ? 0x3F80u : 0u) | ((b8 & 2u)   ? 0x3F800000u : 0u);
            a.u[1] = ((b8 & 4u)  ? 0x3F80u : 0u) | ((b8 & 8u)   ? 0x3F800000u : 0u);
            a.u[2] = ((b8 & 16u) ? 0x3F80u : 0u) | ((b8 & 32u)  ? 0x3F800000u : 0u);
            a.u[3] = ((b8 & 64u) ? 0x3F80u : 0u) | ((b8 & 128u) ? 0x3F800000u : 0u);
            #pragma unroll
            for (int fb = 0; fb < 4; ++fb) {
                short8 b = *(const short8*)&ldsB[(fh + fb * 16 + r16) * 72 + s * 32 + klane * 8];
                acc[fb] = __builtin_amdgcn_mfma_f32_16x16x32_bf16(a.v, b, acc[fb], 0, 0, 0);
            }
        }
        __syncthreads();
    }
    if (FINAL) {
        #pragma unroll
        for (int fb = 0; fb < 4; ++fb)
            #pragma unroll
            for (int r = 0; r < 4; ++r) {
                int row = mbase + klane * 4 + r;
                Cout[(size_t)row * FDIM + fh + fb * 16 + r16] = rowScale[row] * acc[fb][r];
            }
    } else {
        float* P = Cout + (size_t)blockIdx.z * M * FDIM;
        #pragma unroll
        for (int fb = 0; fb < 4; ++fb)
            #pragma unroll
            for (int r = 0; r < 4; ++r) {
                int row = mbase + klane * 4 + r;
                P[(size_t)row * FDIM + fh + fb * 16 + r16] = acc[fb][r];
            }
    }
}

// K5b: sum split-K partials, scale by d_e_inv, write transposed bf16 emT [128][E]
__global__ __launch_bounds__(256) void k_reduce_scale_T(const float* __restrict__ partials,
        const float* __restrict__ deinv, unsigned short* __restrict__ emT, int S) {
    __shared__ float lds[64 * 129];
    int t = threadIdx.x;
    int e0 = blockIdx.x * 64;
    for (int i = 0; i < 32; ++i) {
        int idx = i * 256 + t;
        int e_l = idx >> 7, f = idx & 127;
        float s = 0.f;
        for (int z = 0; z < S; ++z)
            s += partials[(size_t)z * N_EDGES * FDIM + (size_t)(e0 + e_l) * FDIM + f];
        lds[e_l * 129 + f] = s * deinv[e0 + e_l];
    }
    __syncthreads();
    for (int i = 0; i < 32; ++i) {
        int idx = i * 256 + t;
        int f = idx >> 6, e_l = idx & 63;
        emT[(size_t)f * N_EDGES + e0 + e_l] = f2bf(lds[e_l * 129 + f]);
    }
}

extern "C" void kernel_launch(void* const* d_in, const int* in_sizes, int n_in,
                              void* d_out, int out_size, void* d_ws, size_t ws_size,
                              hipStream_t stream) {
    const float* x = (const float*)d_in[0];
    const float* H = (const float*)d_in[1];
    const float* W = (const float*)d_in[2];
    float* out = (float*)d_out;
    char* ws = (char*)d_ws;

    unsigned long long* bitsNE = (unsigned long long*)(ws);                 // 8 MB
    unsigned long long* bitsEN = (unsigned long long*)(ws + (8u << 20));    // 8 MB
    unsigned short* xwT = (unsigned short*)(ws + (16u << 20));              // 4 MB
    unsigned short* emT = (unsigned short*)(ws + (20u << 20));              // 1 MB
    float* dvinv = (float*)(ws + (21u << 20));                              // 64 KB
    float* deinv = (float*)(ws + (21u << 20) + 65536);                      // 16 KB
    size_t pbase = (21u << 20) + 65536 + 16384;
    float* partials = (float*)(ws + pbase);

    int S = 8;  // split-K for the edge GEMM; shrink if workspace is small
    while (S > 1 && pbase + (size_t)S * N_EDGES * FDIM * 4 > ws_size) S >>= 1;

    hipLaunchKernelGGL(k_bitpack, dim3(4096), dim3(256), 0, stream, H, bitsNE, dvinv);
    hipLaunchKernelGGL(k_transpose, dim3(4096), dim3(256), 0, stream, bitsNE, bitsEN);
    hipLaunchKernelGGL(k_edeg, dim3(1024), dim3(256), 0, stream, bitsEN, deinv);
    hipLaunchKernelGGL(k_xw, dim3(256), dim3(256), 0, stream, x, W, xwT);
    hipLaunchKernelGGL((k_gemm_bits<false>), dim3(128, 1, S), dim3(256), 0, stream,
                       bitsEN, N_NODES / 64, xwT, N_NODES, partials, (const float*)nullptr,
                       N_EDGES, (N_NODES / 64) / S);
    hipLaunchKernelGGL(k_reduce_scale_T, dim3(64), dim3(256), 0, stream, partials, deinv, emT, S);
    hipLaunchKernelGGL((k_gemm_bits<true>), dim3(512, 1, 1), dim3(256), 0, stream,
                       bitsNE, N_EDGES / 64, emT, N_EDGES, out, dvinv,
                       N_NODES, N_EDGES / 64);
}

// Round 2
// 264.641 us; speedup vs baseline: 1.1134x; 1.1134x over previous
//
#include <hip/hip_runtime.h>
#include <stdint.h>

#define N_NODES 16384
#define N_EDGES 4096
#define FDIM    128
#define EPSF    1e-6f

typedef __attribute__((ext_vector_type(8))) short short8;
typedef __attribute__((ext_vector_type(4))) float f32x4;
typedef unsigned long long ull;

__device__ __forceinline__ unsigned short f2bf(float f) {
    uint32_t u = __float_as_uint(f);
    return (unsigned short)((u + 0x7FFFu + ((u >> 16) & 1u)) >> 16);  // RNE
}

__device__ __forceinline__ short8 as_s8(uint4 v) {
    union { uint4 a; short8 b; } u; u.a = v; return u.b;
}

// Expand 8 H-bits (byte at bitoff of `half`) into 8 packed bf16 {0.0,1.0}.
// spread: (nib * 0x00204081) & 0x01010101 puts bit i at byte i; perm gathers
// byte pairs into half-word slots; * 0x3F80 turns 0/1 into bf16 1.0.
__device__ __forceinline__ short8 expand8(uint32_t half, int bitoff) {
    uint32_t b8 = (half >> bitoff) & 0xFFu;
    uint32_t lo = ((b8 & 0xFu) * 0x00204081u) & 0x01010101u;
    uint32_t hi = ((b8 >> 4) * 0x00204081u) & 0x01010101u;
    union { short8 v; uint32_t u[4]; } a;
#if __has_builtin(__builtin_amdgcn_perm)
    a.u[0] = __builtin_amdgcn_perm(0u, lo, 0x04010400u) * 0x3F80u;
    a.u[1] = __builtin_amdgcn_perm(0u, lo, 0x04030402u) * 0x3F80u;
    a.u[2] = __builtin_amdgcn_perm(0u, hi, 0x04010400u) * 0x3F80u;
    a.u[3] = __builtin_amdgcn_perm(0u, hi, 0x04030402u) * 0x3F80u;
#else
    a.u[0] = ((lo & 1u)         | ((lo >> 8) & 1u) << 16) * 0x3F80u;
    a.u[1] = (((lo >> 16) & 1u) | ((lo >> 24) & 1u) << 16) * 0x3F80u;
    a.u[2] = ((hi & 1u)         | ((hi >> 8) & 1u) << 16) * 0x3F80u;
    a.u[3] = (((hi >> 16) & 1u) | ((hi >> 24) & 1u) << 16) * 0x3F80u;
#endif
    return a.v;
}

// K1: bitpack H rows -> bitsNE [N][E/64] in permuted bit order
// p(j) = 4*(j&15) + (j>>4), plus exact d_v_inv via popcount.
__global__ __launch_bounds__(256) void k_bitpack(const float* __restrict__ H,
        ull* __restrict__ bitsNE, float* __restrict__ dvinv) {
    int w = threadIdx.x >> 6, lane = threadIdx.x & 63;
    int n = blockIdx.x * 4 + w;
    const float4* hr = (const float4*)(H + (size_t)n * N_EDGES);
    ull* out = bitsNE + (size_t)n * (N_EDGES / 64);
    int cnt = 0;
    for (int c4 = 0; c4 < N_EDGES / 256; ++c4) {
        float4 v = hr[c4 * 64 + lane];
        ull b0 = __ballot(v.x > 0.5f);
        ull b1 = __ballot(v.y > 0.5f);
        ull b2 = __ballot(v.z > 0.5f);
        ull b3 = __ballot(v.w > 0.5f);
        cnt += __popcll(b0) + __popcll(b1) + __popcll(b2) + __popcll(b3);
        if (lane == 0) {
            #pragma unroll
            for (int q = 0; q < 4; ++q) {
                ull wq = ((b0 >> (16 * q)) & 0xFFFFull)
                       | (((b1 >> (16 * q)) & 0xFFFFull) << 16)
                       | (((b2 >> (16 * q)) & 0xFFFFull) << 32)
                       | (((b3 >> (16 * q)) & 0xFFFFull) << 48);
                out[c4 * 4 + q] = wq;
            }
        }
    }
    if (lane == 0) dvinv[n] = 1.0f / ((float)cnt + EPSF);
}

// K2: 64x64 bit-tile transpose with the same permuted order on both sides.
__global__ __launch_bounds__(256) void k_transpose(const ull* __restrict__ bitsNE,
        ull* __restrict__ bitsEN) {
    int w = threadIdx.x >> 6, lane = threadIdx.x & 63;
    int wid = blockIdx.x * 4 + w;
    int et = wid & 63, nt = wid >> 6;
    int pl = 4 * (lane & 15) + (lane >> 4);
    ull q = bitsNE[(size_t)(nt * 64 + pl) * (N_EDGES / 64) + et];
    ull outv = 0;
    for (int j = 0; j < 64; ++j) {
        ull r = __ballot((int)((q >> j) & 1ULL));
        if (lane == j) outv = r;
    }
    bitsEN[(size_t)(et * 64 + pl) * (N_NODES / 64) + nt] = outv;
}

// K3: edge degrees via popcount -> d_e_inv (permutation-invariant, exact)
__global__ __launch_bounds__(256) void k_edeg(const ull* __restrict__ bitsEN,
        float* __restrict__ deinv) {
    int w = threadIdx.x >> 6, lane = threadIdx.x & 63;
    int e = blockIdx.x * 4 + w;
    const ull* r = bitsEN + (size_t)e * (N_NODES / 64);
    int s = __popcll(r[lane]) + __popcll(r[lane + 64]) + __popcll(r[lane + 128]) + __popcll(r[lane + 192]);
    for (int o = 32; o; o >>= 1) s += __shfl_xor(s, o);
    if (lane == 0) deinv[e] = 1.0f / ((float)s + EPSF);
}

// K4: xw = x @ W via MFMA; output transposed bf16 xwTp [128][N] with node
// columns permuted within each 64-chunk (inverse perm applied in LDS epilogue).
__global__ __launch_bounds__(256) void k_xw(const float* __restrict__ x, const float* __restrict__ W,
        unsigned short* __restrict__ xwTp) {
    __shared__ __attribute__((aligned(16))) unsigned short ldsWT[128 * 136];
    __shared__ __attribute__((aligned(16))) unsigned short ldsT[128 * 72];
    int t = threadIdx.x, lane = t & 63, w = t >> 6;
    int r16 = lane & 15, klane = lane >> 4;
    for (int i = 0; i < 64; ++i) {
        int idx = i * 256 + t;
        int k = idx >> 7, f = idx & 127;
        ldsWT[f * 136 + k] = f2bf(W[idx]);
    }
    __syncthreads();
    int nbase = blockIdx.x * 64;
    int row = nbase + w * 16 + r16;
    const float4* xr4 = (const float4*)(x + (size_t)row * FDIM);
    f32x4 acc[8] = {};
    for (int kb = 0; kb < 128; kb += 32) {
        float4 u0 = xr4[(kb >> 2) + klane * 2];
        float4 u1 = xr4[(kb >> 2) + klane * 2 + 1];
        union { short8 v; unsigned short u[8]; } a;
        a.u[0] = f2bf(u0.x); a.u[1] = f2bf(u0.y); a.u[2] = f2bf(u0.z); a.u[3] = f2bf(u0.w);
        a.u[4] = f2bf(u1.x); a.u[5] = f2bf(u1.y); a.u[6] = f2bf(u1.z); a.u[7] = f2bf(u1.w);
        #pragma unroll
        for (int fb = 0; fb < 8; ++fb) {
            short8 b = *(const short8*)&ldsWT[(fb * 16 + r16) * 136 + kb + klane * 8];
            acc[fb] = __builtin_amdgcn_mfma_f32_16x16x32_bf16(a.v, b, acc[fb], 0, 0, 0);
        }
    }
    // local node nl = w*16 + klane*4 + r; invp(nl) = 16*r + w*4 + klane
    #pragma unroll
    for (int fb = 0; fb < 8; ++fb)
        #pragma unroll
        for (int r = 0; r < 4; ++r)
            ldsT[(fb * 16 + r16) * 72 + 16 * r + w * 4 + klane] = f2bf(acc[fb][r]);
    __syncthreads();
    int f = t >> 1, part = t & 1;
    #pragma unroll
    for (int j = 0; j < 4; ++j)
        *(uint4*)&xwTp[(size_t)f * N_NODES + nbase + part * 32 + j * 8] =
            *(const uint4*)&ldsT[f * 72 + part * 32 + j * 8];
}

#define LOADP(Q0, Q1, BUF, p) do { \
    Q0 = brow0[(p)]; Q1 = brow1[(p)]; \
    const unsigned short* _src = bcol + (size_t)(p) * 64; \
    _Pragma("unroll") \
    for (int _fb = 0; _fb < 4; ++_fb) { \
        BUF[_fb * 2]     = *(const uint4*)(_src + _fb * fbstride); \
        BUF[_fb * 2 + 1] = *(const uint4*)(_src + _fb * fbstride + 32); \
    } } while (0)

#define COMPUTEP(Q0, Q1, BUF) do { \
    _Pragma("unroll") \
    for (int _s = 0; _s < 2; ++_s) { \
        uint32_t _h0 = (uint32_t)(_s == 0 ? (Q0) : ((Q0) >> 32)); \
        uint32_t _h1 = (uint32_t)(_s == 0 ? (Q1) : ((Q1) >> 32)); \
        short8 _a0 = expand8(_h0, bitoff); \
        short8 _a1 = expand8(_h1, bitoff); \
        _Pragma("unroll") \
        for (int _fb = 0; _fb < 4; ++_fb) { \
            short8 _b = as_s8(BUF[_fb * 2 + _s]); \
            acc[0][_fb] = __builtin_amdgcn_mfma_f32_16x16x32_bf16(_a0, _b, acc[0][_fb], 0, 0, 0); \
            acc[1][_fb] = __builtin_amdgcn_mfma_f32_16x16x32_bf16(_a1, _b, acc[1][_fb], 0, 0, 0); \
        } } } while (0)

// Barrier-free bit-GEMM: C[M,128] = bits * BT^T, B-fragments direct from L2,
// A expanded from bits in-register. Wave = 32 rows x 64 cols; block = 2Mx2F.
template<bool FINAL>
__global__ __launch_bounds__(256) void k_gemm_bits(
        const ull* __restrict__ bits, int krows,
        const unsigned short* __restrict__ BT, int K,
        float* __restrict__ Cout, const float* __restrict__ rowScale,
        int M, int pairs) {
    int t = threadIdx.x, lane = t & 63, w = t >> 6;
    int r16 = lane & 15, klane = lane >> 4;
    int bitoff = klane * 8;
    int wm = w >> 1, wf = w & 1;
    int mbase = blockIdx.x * 64 + wm * 32;
    int kw0 = blockIdx.z * pairs;
    const ull* brow0 = bits + (size_t)(mbase + r16) * krows + kw0;
    const ull* brow1 = brow0 + (size_t)16 * krows;
    const unsigned short* bcol = BT + (size_t)(wf * 64 + r16) * K + (size_t)kw0 * 64 + klane * 8;
    const int fbstride = 16 * K;

    f32x4 acc[2][4] = {};
    ull qA0, qA1, qB0, qB1;
    uint4 bufA[8], bufB[8];

    LOADP(qA0, qA1, bufA, 0);
    for (int p = 0; p < pairs; p += 2) {
        LOADP(qB0, qB1, bufB, p + 1);
        COMPUTEP(qA0, qA1, bufA);
        if (p + 2 < pairs) LOADP(qA0, qA1, bufA, p + 2);
        COMPUTEP(qB0, qB1, bufB);
    }

    #pragma unroll
    for (int fr = 0; fr < 2; ++fr)
        #pragma unroll
        for (int fb = 0; fb < 4; ++fb)
            #pragma unroll
            for (int r = 0; r < 4; ++r) {
                int row = mbase + fr * 16 + klane * 4 + r;
                int col = wf * 64 + fb * 16 + r16;
                float v = acc[fr][fb][r];
                if (FINAL)
                    Cout[(size_t)row * FDIM + col] = rowScale[row] * v;
                else
                    Cout[(size_t)blockIdx.z * M * FDIM + (size_t)row * FDIM + col] = v;
            }
}

// K5b: reduce split-K partials, scale by d_e_inv, write transposed bf16
// emTp [128][E] with edge columns permuted within 64-chunks.
__global__ __launch_bounds__(256) void k_reduce_scale_T(const float* __restrict__ partials,
        const float* __restrict__ deinv, unsigned short* __restrict__ emTp, int S) {
    __shared__ float lds[64 * 129];
    int t = threadIdx.x;
    int e0 = blockIdx.x * 64;
    for (int i = 0; i < 32; ++i) {
        int idx = i * 256 + t;
        int e_l = idx >> 7, f = idx & 127;
        float s = 0.f;
        for (int z = 0; z < S; ++z)
            s += partials[(size_t)z * N_EDGES * FDIM + (size_t)(e0 + e_l) * FDIM + f];
        lds[e_l * 129 + f] = s * deinv[e0 + e_l];
    }
    __syncthreads();
    for (int i = 0; i < 32; ++i) {
        int idx = i * 256 + t;
        int f = idx >> 6, j = idx & 63;
        int pj = 4 * (j & 15) + (j >> 4);
        emTp[(size_t)f * N_EDGES + e0 + j] = f2bf(lds[pj * 129 + f]);
    }
}

extern "C" void kernel_launch(void* const* d_in, const int* in_sizes, int n_in,
                              void* d_out, int out_size, void* d_ws, size_t ws_size,
                              hipStream_t stream) {
    const float* x = (const float*)d_in[0];
    const float* H = (const float*)d_in[1];
    const float* W = (const float*)d_in[2];
    float* out = (float*)d_out;
    char* ws = (char*)d_ws;

    ull* bitsNE = (ull*)(ws);                                   // 8 MB
    ull* bitsEN = (ull*)(ws + (8u << 20));                      // 8 MB
    unsigned short* xwTp = (unsigned short*)(ws + (16u << 20)); // 4 MB
    unsigned short* emTp = (unsigned short*)(ws + (20u << 20)); // 1 MB
    float* dvinv = (float*)(ws + (21u << 20));                  // 64 KB
    float* deinv = (float*)(ws + (21u << 20) + 65536);          // 16 KB
    size_t pbase = (21u << 20) + 65536 + 16384;
    float* partials = (float*)(ws + pbase);

    int S = 4;  // split-K for the edge GEMM
    while (S > 1 && pbase + (size_t)S * N_EDGES * FDIM * 4 > ws_size) S >>= 1;

    hipLaunchKernelGGL(k_bitpack, dim3(4096), dim3(256), 0, stream, H, bitsNE, dvinv);
    hipLaunchKernelGGL(k_transpose, dim3(4096), dim3(256), 0, stream, bitsNE, bitsEN);
    hipLaunchKernelGGL(k_edeg, dim3(1024), dim3(256), 0, stream, bitsEN, deinv);
    hipLaunchKernelGGL(k_xw, dim3(256), dim3(256), 0, stream, x, W, xwTp);
    hipLaunchKernelGGL((k_gemm_bits<false>), dim3(64, 1, S), dim3(256), 0, stream,
                       bitsEN, N_NODES / 64, xwTp, N_NODES, partials, (const float*)nullptr,
                       N_EDGES, (N_NODES / 64) / S);
    hipLaunchKernelGGL(k_reduce_scale_T, dim3(64), dim3(256), 0, stream, partials, deinv, emTp, S);
    hipLaunchKernelGGL((k_gemm_bits<true>), dim3(256, 1, 1), dim3(256), 0, stream,
                       bitsNE, N_EDGES / 64, emTp, N_EDGES, out, dvinv,
                       N_NODES, N_EDGES / 64);
}